// Round 2
// baseline (220.420 us; speedup 1.0000x reference)
//
#include <hip/hip_runtime.h>
#include <hip/hip_bf16.h>
#include <math.h>

#define BS   128
#define NT   25
#define CREC 107
#define CLOC 25
#define QN   1024      // H*W = 32*32 queries = columns of the transposed cost
#define INFD 1e18
#define KPL  16        // columns per lane (QN / 64)

// focal-loss matcher cost: pos - neg for sigmoid prob p, f32 exactly as reference
__device__ __forceinline__ float focal_cost_f(float x) {
    float p   = 1.0f / (1.0f + expf(-x));
    float neg = 0.75f * p * p * (-logf(1.0f - p + 1e-8f));
    float pos = 0.25f * (1.0f - p) * (1.0f - p) * (-logf(p + 1e-8f));
    return pos - neg;
}

// C[b][t][q] = 2*focal(sigmoid(rec[b, targets[b,t], q])) + focal(sigmoid(loc[b, t, q]))
__global__ void cost_kernel(const float* __restrict__ rec, const float* __restrict__ loc,
                            const int* __restrict__ targets, float* __restrict__ cost) {
    int bid = blockIdx.x;            // b*NT + t
    int b = bid / NT, t = bid % NT;
    int tc = targets[b * NT + t];
    const float* rrow = rec + ((size_t)b * CREC + tc) * QN;
    const float* lrow = loc + ((size_t)b * CLOC + t) * QN;
    float* crow = cost + (size_t)bid * QN;
    for (int q = threadIdx.x; q < QN; q += blockDim.x) {
        crow[q] = 2.0f * focal_cost_f(rrow[q]) + focal_cost_f(lrow[q]);
    }
}

// One block = ONE WAVE per batch. JV shortest-augmenting-path with all column
// state (minv, v, used) in per-lane registers; argmin via shuffle butterfly.
// Only way/p (dynamic-index in augmentation) and u (scattered RMW) live in LDS.
// f64 potentials => bit-identical assignment to the numpy float64 reference.
__global__ __launch_bounds__(64)
void hungarian_loss_kernel(const float* __restrict__ cost,
                           const float* __restrict__ rec, const float* __restrict__ loc,
                           const int* __restrict__ targets, float* __restrict__ out) {
    const int b    = blockIdx.x;
    const int lane = threadIdx.x;     // 0..63, one wave

    __shared__ int    way_s[QN + 1];
    __shared__ int    p_s[QN + 1];
    __shared__ double u_s[NT + 2];
    __shared__ int    pairq[NT];

    for (int j = lane; j <= QN; j += 64) { p_s[j] = 0; way_s[j] = 0; }
    if (lane < NT + 2) u_s[lane] = 0.0;
    __syncthreads();

    const float* cbase = cost ? (cost + (size_t)b * NT * QN) : nullptr;

    // lane 'lane' owns columns j = 1 + lane + 64*k, k = 0..15
    double v[KPL];
    #pragma unroll
    for (int k = 0; k < KPL; ++k) v[k] = 0.0;

    for (int i = 1; i <= NT; ++i) {
        double minv[KPL];
        unsigned usedmask = 0;
        #pragma unroll
        for (int k = 0; k < KPL; ++k) minv[k] = INFD;

        int j0 = 0;
        for (int iter = 0; iter < QN + 2; ++iter) {
            // mark j0 used (owner lane); resolve row i0 = p[j0]
            int i0;
            if (j0 == 0) {
                i0 = i;
            } else {
                if (((j0 - 1) & 63) == lane) {
                    int kk = (j0 - 1) >> 6;
                    usedmask |= 1u << kk;
                    minv[kk] = INFD;     // masked out of argmin, excluded from -=delta
                }
                i0 = p_s[j0];            // p stable within a round
            }
            const double ui0 = u_s[i0];  // prev iteration's u updates fenced by barrier

            // fetch this row's cost for own columns (coalesced 256B/load, L2-hot)
            float cf[KPL];
            if (cbase) {
                const float* crow = cbase + (size_t)(i0 - 1) * QN;
                #pragma unroll
                for (int k = 0; k < KPL; ++k) cf[k] = crow[lane + 64 * k];
            } else {
                int tc = targets[b * NT + (i0 - 1)];
                const float* rrow = rec + ((size_t)b * CREC + tc) * QN;
                const float* lrow = loc + ((size_t)b * CLOC + (i0 - 1)) * QN;
                #pragma unroll
                for (int k = 0; k < KPL; ++k) {
                    int q = lane + 64 * k;
                    cf[k] = 2.0f * focal_cost_f(rrow[q]) + focal_cost_f(lrow[q]);
                }
            }

            // relax free columns; track lane-local argmin (first-index ties)
            double bestv = INFD; int bestj = QN + 2;
            #pragma unroll
            for (int k = 0; k < KPL; ++k) {
                if (!(usedmask & (1u << k))) {
                    const int j = 1 + lane + 64 * k;
                    double cur = (double)cf[k] - ui0 - v[k];
                    if (cur < minv[k]) { minv[k] = cur; way_s[j] = j0; }
                    double mv = minv[k];
                    if (mv < bestv || (mv == bestv && j < bestj)) { bestv = mv; bestj = j; }
                }
            }
            // wave-wide lexicographic (value, index) min — no LDS, no barriers
            #pragma unroll
            for (int off = 32; off; off >>= 1) {
                double ov = __shfl_xor(bestv, off);
                int    oj = __shfl_xor(bestj, off);
                if (ov < bestv || (ov == bestv && oj < bestj)) { bestv = ov; bestj = oj; }
            }
            const double delta = bestv;
            const int j1 = bestj;

            // v[used] -= delta (regs); minv[free] -= delta (regs)
            #pragma unroll
            for (int k = 0; k < KPL; ++k) {
                if (usedmask & (1u << k)) v[k]    -= delta;
                else                      minv[k] -= delta;
            }
            // u[p[used]] += delta: j=0 column (p[0]=i, always used) + own used cols.
            // Distinct rows per used column => conflict-free scattered RMW.
            if (lane == 0) u_s[i] += delta;
            unsigned m = usedmask;
            while (m) {
                int k = __ffs(m) - 1; m &= m - 1;
                int j = 1 + lane + 64 * k;
                u_s[p_s[j]] += delta;
            }
            __syncthreads();   // fence u_s (and eventually way_s) for next iter/augment

            j0 = j1;
            if (p_s[j0] == 0) break;
        }
        // augment along the alternating path (short, sequential)
        if (lane == 0) {
            int jj = j0;
            while (jj != 0) {
                int jn = way_s[jj];
                p_s[jj] = (jn == 0) ? i : p_s[jn];
                jj = jn;
            }
        }
        __syncthreads();
    }

    // collect matched pairs: column j assigned to target row p_s[j]-1
    for (int j = lane + 1; j <= QN; j += 64)
        if (p_s[j] > 0) pairq[p_s[j] - 1] = j - 1;
    __syncthreads();

    // fused CE losses; the mean is permutation-invariant so no sorting needed
    float recsum = 0.0f, locsum = 0.0f;
    for (int t = 0; t < NT; ++t) {
        const int q = pairq[t];

        // rec CE over 107 classes at query q
        const float* rb = rec + (size_t)b * CREC * QN + q;
        float x0 = (lane < CREC)      ? rb[(size_t)lane * QN]        : -1e30f;
        float x1 = (lane + 64 < CREC) ? rb[(size_t)(lane + 64) * QN] : -1e30f;
        float mx = fmaxf(x0, x1);
        #pragma unroll
        for (int off = 32; off; off >>= 1) mx = fmaxf(mx, __shfl_xor(mx, off));
        float e = 0.0f;
        if (lane < CREC)      e += expf(x0 - mx);
        if (lane + 64 < CREC) e += expf(x1 - mx);
        #pragma unroll
        for (int off = 32; off; off >>= 1) e += __shfl_xor(e, off);
        float lse = mx + logf(e);
        int lab = targets[b * NT + t];
        recsum += lse - rb[(size_t)lab * QN];

        // loc CE over 25 classes at query q, label = t
        const float* lb = loc + (size_t)b * CLOC * QN + q;
        float y = (lane < CLOC) ? lb[(size_t)lane * QN] : -1e30f;
        float my = y;
        #pragma unroll
        for (int off = 32; off; off >>= 1) my = fmaxf(my, __shfl_xor(my, off));
        float ey = (lane < CLOC) ? expf(y - my) : 0.0f;
        #pragma unroll
        for (int off = 32; off; off >>= 1) ey += __shfl_xor(ey, off);
        float lsey = my + logf(ey);
        locsum += lsey - lb[(size_t)t * QN];
    }
    if (lane == 0) {
        atomicAdd(&out[0], recsum * (1.0f / (BS * NT)));
        atomicAdd(&out[1], locsum * (1.0f / (BS * NT)));
    }
}

extern "C" void kernel_launch(void* const* d_in, const int* in_sizes, int n_in,
                              void* d_out, int out_size, void* d_ws, size_t ws_size,
                              hipStream_t stream) {
    (void)in_sizes; (void)n_in; (void)out_size;
    const float* rec     = (const float*)d_in[0];
    const float* loc     = (const float*)d_in[1];
    const int*   targets = (const int*)d_in[2];
    float* out = (float*)d_out;

    hipMemsetAsync(d_out, 0, 2 * sizeof(float), stream);

    const size_t cost_bytes = (size_t)BS * NT * QN * sizeof(float);
    float* cost = nullptr;
    if (ws_size >= cost_bytes) {
        cost = (float*)d_ws;
        hipLaunchKernelGGL(cost_kernel, dim3(BS * NT), dim3(256), 0, stream,
                           rec, loc, targets, cost);
    }
    hipLaunchKernelGGL(hungarian_loss_kernel, dim3(BS), dim3(64), 0, stream,
                       cost, rec, loc, targets, out);
}

// Round 3
// 193.083 us; speedup vs baseline: 1.1416x; 1.1416x over previous
//
#include <hip/hip_runtime.h>
#include <hip/hip_bf16.h>
#include <math.h>

#define BS   128
#define NT   25
#define CREC 107
#define CLOC 25
#define QN   1024      // H*W = 32*32 queries = columns of the transposed cost
#define INFD 1e18
#define KPL  16        // columns per lane (QN / 64)

// focal-loss matcher cost: pos - neg for sigmoid prob p, f32 exactly as reference
__device__ __forceinline__ float focal_cost_f(float x) {
    float p   = 1.0f / (1.0f + expf(-x));
    float neg = 0.75f * p * p * (-logf(1.0f - p + 1e-8f));
    float pos = 0.25f * (1.0f - p) * (1.0f - p) * (-logf(p + 1e-8f));
    return pos - neg;
}

// C[b][t][q] = 2*focal(sigmoid(rec[b, targets[b,t], q])) + focal(sigmoid(loc[b, t, q]))
// 256 threads x one float4 each = 1024 cols per row.
__global__ __launch_bounds__(256)
void cost_kernel(const float* __restrict__ rec, const float* __restrict__ loc,
                 const int* __restrict__ targets, float* __restrict__ cost) {
    int bid = blockIdx.x;            // b*NT + t
    int b = bid / NT, t = bid % NT;
    int tc = targets[b * NT + t];
    const float4* rrow = (const float4*)(rec + ((size_t)b * CREC + tc) * QN);
    const float4* lrow = (const float4*)(loc + ((size_t)b * CLOC + t) * QN);
    float4* crow = (float4*)(cost + (size_t)bid * QN);
    int q = threadIdx.x;
    float4 r = rrow[q], l = lrow[q], c;
    c.x = 2.0f * focal_cost_f(r.x) + focal_cost_f(l.x);
    c.y = 2.0f * focal_cost_f(r.y) + focal_cost_f(l.y);
    c.z = 2.0f * focal_cost_f(r.z) + focal_cost_f(l.z);
    c.w = 2.0f * focal_cost_f(r.w) + focal_cost_f(l.w);
    crow[q] = c;
}

// One block = ONE WAVE per batch. JV shortest-augmenting-path with all column
// state (minv, v, used) in per-lane registers; argmin via shuffle butterfly.
// Lane owns columns q = 4*lane + m + 256*g (m,g in 0..3) so the per-row fetch
// is 4x global_load_dwordx4. f64 potentials => exact numpy float64 semantics.
// Writes the assignment (pairq) to global for the parallel loss kernel.
__global__ __launch_bounds__(64)
void hungarian_kernel(const float* __restrict__ cost,
                      const float* __restrict__ rec, const float* __restrict__ loc,
                      const int* __restrict__ targets, int* __restrict__ pairq_g) {
    const int b    = blockIdx.x;
    const int lane = threadIdx.x;     // 0..63, one wave

    __shared__ int    way_s[QN + 1];
    __shared__ int    p_s[QN + 1];
    __shared__ double u_s[NT + 2];

    for (int j = lane; j <= QN; j += 64) { p_s[j] = 0; way_s[j] = 0; }
    if (lane < NT + 2) u_s[lane] = 0.0;
    __syncthreads();

    const float* cbase = cost + (size_t)b * NT * QN;

    // column for slot k (k = g*4 + m): q = 4*lane + m + 256*g, j = q+1
    double v[KPL];
    #pragma unroll
    for (int k = 0; k < KPL; ++k) v[k] = 0.0;

    for (int i = 1; i <= NT; ++i) {
        double minv[KPL];
        unsigned usedmask = 0;
        #pragma unroll
        for (int k = 0; k < KPL; ++k) minv[k] = INFD;

        int j0 = 0;
        for (int iter = 0; iter < QN + 2; ++iter) {
            // mark j0 used (owner lane); resolve row i0 = p[j0]
            int i0;
            if (j0 == 0) {
                i0 = i;
            } else {
                int q0 = j0 - 1;
                if (((q0 >> 2) & 63) == lane) {
                    int kk = ((q0 >> 8) << 2) | (q0 & 3);
                    usedmask |= 1u << kk;
                    minv[kk] = INFD;     // masked out of argmin, excluded from -=delta
                }
                i0 = p_s[j0];            // p stable within a round
            }
            const double ui0 = u_s[i0];  // prev iteration's u updates fenced by barrier

            // fetch this row's cost for own columns: 4x dwordx4, coalesced
            float cf[KPL];
            const float* crow = cbase + (size_t)(i0 - 1) * QN;
            #pragma unroll
            for (int g = 0; g < 4; ++g) {
                float4 c4 = *(const float4*)(crow + 4 * lane + 256 * g);
                cf[g * 4 + 0] = c4.x; cf[g * 4 + 1] = c4.y;
                cf[g * 4 + 2] = c4.z; cf[g * 4 + 3] = c4.w;
            }

            // relax free columns; track lane-local argmin (first-index ties)
            double bestv = INFD; int bestj = QN + 2;
            #pragma unroll
            for (int k = 0; k < KPL; ++k) {
                if (!(usedmask & (1u << k))) {
                    const int j = 1 + 4 * lane + (k & 3) + 256 * (k >> 2);
                    double cur = (double)cf[k] - ui0 - v[k];
                    if (cur < minv[k]) { minv[k] = cur; way_s[j] = j0; }
                    double mv = minv[k];
                    if (mv < bestv || (mv == bestv && j < bestj)) { bestv = mv; bestj = j; }
                }
            }
            // wave-wide lexicographic (value, index) min — no LDS, no barriers
            #pragma unroll
            for (int off = 32; off; off >>= 1) {
                double ov = __shfl_xor(bestv, off);
                int    oj = __shfl_xor(bestj, off);
                if (ov < bestv || (ov == bestv && oj < bestj)) { bestv = ov; bestj = oj; }
            }
            const double delta = bestv;
            const int j1 = bestj;

            // v[used] -= delta (regs); minv[free] -= delta (regs)
            #pragma unroll
            for (int k = 0; k < KPL; ++k) {
                if (usedmask & (1u << k)) v[k]    -= delta;
                else                      minv[k] -= delta;
            }
            // u[p[used]] += delta: j=0 column (p[0]=i, always used) + own used cols.
            // Distinct rows per used column => conflict-free scattered RMW.
            if (lane == 0) u_s[i] += delta;
            unsigned m = usedmask;
            while (m) {
                int k = __ffs(m) - 1; m &= m - 1;
                int j = 1 + 4 * lane + (k & 3) + 256 * (k >> 2);
                u_s[p_s[j]] += delta;
            }
            __syncthreads();   // fence u_s / way_s for next iter & augment

            j0 = j1;
            if (p_s[j0] == 0) break;
        }
        // augment along the alternating path (short, sequential)
        if (lane == 0) {
            int jj = j0;
            while (jj != 0) {
                int jn = way_s[jj];
                p_s[jj] = (jn == 0) ? i : p_s[jn];
                jj = jn;
            }
        }
        __syncthreads();
    }

    // emit matched pairs: column j assigned to target row p_s[j]-1
    for (int j = lane + 1; j <= QN; j += 64)
        if (p_s[j] > 0) pairq_g[b * NT + (p_s[j] - 1)] = j - 1;
}

// One wave per matched pair: CE over 107 (rec) and 25 (loc) classes at the
// matched query column. 3200 blocks => full latency hiding for the gathers.
__global__ __launch_bounds__(64)
void loss_kernel(const float* __restrict__ rec, const float* __restrict__ loc,
                 const int* __restrict__ targets, const int* __restrict__ pairq_g,
                 float* __restrict__ partial) {
    const int pid  = blockIdx.x;          // b*NT + t
    const int b    = pid / NT, t = pid % NT;
    const int lane = threadIdx.x;
    const int q    = pairq_g[pid];

    // rec CE over 107 classes at query q
    const float* rb = rec + (size_t)b * CREC * QN + q;
    float x0 = (lane < CREC)      ? rb[(size_t)lane * QN]        : -1e30f;
    float x1 = (lane + 64 < CREC) ? rb[(size_t)(lane + 64) * QN] : -1e30f;
    float mx = fmaxf(x0, x1);
    #pragma unroll
    for (int off = 32; off; off >>= 1) mx = fmaxf(mx, __shfl_xor(mx, off));
    float e = 0.0f;
    if (lane < CREC)      e += expf(x0 - mx);
    if (lane + 64 < CREC) e += expf(x1 - mx);
    #pragma unroll
    for (int off = 32; off; off >>= 1) e += __shfl_xor(e, off);
    float lse = mx + logf(e);

    // loc CE over 25 classes at query q, label = t
    const float* lb = loc + (size_t)b * CLOC * QN + q;
    float y = (lane < CLOC) ? lb[(size_t)lane * QN] : -1e30f;
    float my = y;
    #pragma unroll
    for (int off = 32; off; off >>= 1) my = fmaxf(my, __shfl_xor(my, off));
    float ey = (lane < CLOC) ? expf(y - my) : 0.0f;
    #pragma unroll
    for (int off = 32; off; off >>= 1) ey += __shfl_xor(ey, off);
    float lsey = my + logf(ey);

    if (lane == 0) {
        int lab = targets[pid];
        partial[pid]           = lse  - rb[(size_t)lab * QN];
        partial[BS * NT + pid] = lsey - lb[(size_t)t * QN];
    }
}

__global__ __launch_bounds__(256)
void finalize_kernel(const float* __restrict__ partial, float* __restrict__ out) {
    const int tid = threadIdx.x;
    float s0 = 0.0f, s1 = 0.0f;
    for (int i = tid; i < BS * NT; i += 256) {
        s0 += partial[i];
        s1 += partial[BS * NT + i];
    }
    __shared__ float a0[4], a1[4];
    #pragma unroll
    for (int off = 32; off; off >>= 1) { s0 += __shfl_xor(s0, off); s1 += __shfl_xor(s1, off); }
    if ((tid & 63) == 0) { a0[tid >> 6] = s0; a1[tid >> 6] = s1; }
    __syncthreads();
    if (tid == 0) {
        out[0] = (a0[0] + a0[1] + a0[2] + a0[3]) * (1.0f / (BS * NT));
        out[1] = (a1[0] + a1[1] + a1[2] + a1[3]) * (1.0f / (BS * NT));
    }
}

extern "C" void kernel_launch(void* const* d_in, const int* in_sizes, int n_in,
                              void* d_out, int out_size, void* d_ws, size_t ws_size,
                              hipStream_t stream) {
    (void)in_sizes; (void)n_in; (void)out_size; (void)ws_size;
    const float* rec     = (const float*)d_in[0];
    const float* loc     = (const float*)d_in[1];
    const int*   targets = (const int*)d_in[2];
    float* out = (float*)d_out;

    // workspace layout: cost [13.1 MB] | pairq [3200 int] | partial [6400 f32]
    float* cost    = (float*)d_ws;
    int*   pairq_g = (int*)((char*)d_ws + (size_t)BS * NT * QN * sizeof(float));
    float* partial = (float*)(pairq_g + BS * NT);

    hipLaunchKernelGGL(cost_kernel, dim3(BS * NT), dim3(256), 0, stream,
                       rec, loc, targets, cost);
    hipLaunchKernelGGL(hungarian_kernel, dim3(BS), dim3(64), 0, stream,
                       cost, rec, loc, targets, pairq_g);
    hipLaunchKernelGGL(loss_kernel, dim3(BS * NT), dim3(64), 0, stream,
                       rec, loc, targets, pairq_g, partial);
    hipLaunchKernelGGL(finalize_kernel, dim3(1), dim3(256), 0, stream,
                       partial, out);
}